// Round 1
// baseline (310.728 us; speedup 1.0000x reference)
//
#include <hip/hip_runtime.h>

#define NN 256

// ---- combo tables: 15 (l1,l2,L) CG tensors, dense [2l1+1][2l2+1][2L+1] ----
__device__ const int COMBO_L1[15]  = {0,0,1,1,1,1,0,2,1,2,1,2,2,2,2};
__device__ const int COMBO_L2[15]  = {0,1,0,1,1,1,2,0,2,1,2,1,2,2,2};
__device__ const int COMBO_LL[15]  = {0,1,1,0,1,2,2,2,1,1,2,2,0,1,2};
__device__ const int COMBO_OFF[15] = {0,1,10,19,28,55,100,125,150,195,240,315,390,415,490};
// chunk order per output L (reference loop order l1 then l2):
// L=0: (0,0),(1,1),(2,2)   L=1: (0,1),(1,0),(1,1),(1,2),(2,1),(2,2)
// L=2: (0,2),(1,1),(1,2),(2,0),(2,1),(2,2)
__device__ const int CHUNK_COMBO[15] = {0,3,12, 1,2,4,8,9,13, 6,5,10,7,11,14};
__device__ const int LSTART[3] = {0,3,9};
__device__ const int MB[3] = {0,1,4};   // m-index base per l (and s-index base)

// ---------------- CG coefficient init (double, exact replica of ref) -------
__device__ double dfact(int n){ double r=1.0; for(int i=2;i<=n;i++) r*=i; return r; }

__device__ double cg_coeff(int j1,int m1,int j2,int m2,int J,int M){
  if (m1+m2 != M || J < abs(j1-j2) || J > j1+j2) return 0.0;
  double pre = sqrt((2.0*J+1.0)*dfact(J+j1-j2)*dfact(J-j1+j2)*dfact(j1+j2-J)/dfact(j1+j2+J+1));
  pre *= sqrt(dfact(J+M)*dfact(J-M)*dfact(j1-m1)*dfact(j1+m1)*dfact(j2-m2)*dfact(j2+m2));
  int kmin = max(0, max(j2-J-m1, j1+m2-J));
  int kmax = min(j1+j2-J, min(j1-m1, j2+m2));
  double s = 0.0;
  for (int k=kmin;k<=kmax;k++){
    double den = dfact(k)*dfact(j1+j2-J-k)*dfact(j1-m1-k)*dfact(j2+m2-k)*dfact(J-j2+m1+k)*dfact(J-j1-m2+k);
    s += ((k&1)?-1.0:1.0)/den;
  }
  return pre*s;
}

__global__ void init_cg(float* cg){
  int t = threadIdx.x;
  if (t >= 15) return;
  int l1 = COMBO_L1[t], l2 = COMBO_L2[t], L = COMBO_LL[t], off = COMBO_OFF[t];
  int sz = (2*l1+1)*(2*l2+1)*(2*L+1);
  for (int i=0;i<sz;i++) cg[off+i] = 0.f;
  for (int m1=-l1;m1<=l1;m1++)
    for (int m2=-l2;m2<=l2;m2++){
      int M = m1+m2;
      if (M >= -L && M <= L)
        cg[off + ((m1+l1)*(2*l2+1) + (m2+l2))*(2*L+1) + (M+L)] = (float)cg_coeff(l1,m1,l2,m2,L,M);
    }
}

// ---------------- kernel 1: vmp = adj @ v  -> [256][72] --------------------
__global__ void k_vmp(const float* __restrict__ adj,
                      const float* __restrict__ v0,
                      const float* __restrict__ v1,
                      const float* __restrict__ v2,
                      float* __restrict__ vmp){
  int i = blockIdx.x;
  int t = threadIdx.x;
  if (t >= 72) return;
  int mall = t >> 3, c = t & 7;
  int l = (mall==0) ? 0 : (mall < 4 ? 1 : 2);
  int m = mall - MB[l];
  const float* v = (l==0) ? v0 : (l==1 ? v1 : v2);
  int stride = (2*l+1)*8;
  const float* arow = adj + i*NN;
  float acc = 0.f;
  for (int j=0;j<NN;j++) acc += arow[j] * v[j*stride + m*8 + c];
  vmp[i*72 + t] = acc;
}

// ---------------- kernel 2: per-node CG(vmp,vmp) + wn mix -> mixed[256][72]
__global__ void k_mixed(const float* __restrict__ vmp,
                        const float* __restrict__ wn0,
                        const float* __restrict__ wn1,
                        const float* __restrict__ wn2,
                        const float* __restrict__ cg,
                        float* __restrict__ mixed){
  __shared__ float vb[72];
  __shared__ float cgb[3264];   // L0: [0,192)  L1: 192+M*384  L2: 1344+M*384
  int i = blockIdx.x;
  int t = threadIdx.x;
  if (t < 72) vb[t] = vmp[i*72 + t];
  __syncthreads();
  for (int v = t; v < 3264; v += blockDim.x){
    int L, M, ch;
    if (v < 192)       { L=0; M=0;            ch=v; }
    else if (v < 1344) { int r=v-192;  L=1; M=r/384; ch=r%384; }
    else               { int r=v-1344; L=2; M=r/384; ch=r%384; }
    int chunk = ch >> 6, rem = ch & 63, c = rem >> 3, d = rem & 7;
    int combo = CHUNK_COMBO[LSTART[L] + chunk];
    int l1 = COMBO_L1[combo], l2 = COMBO_L2[combo], off = COMBO_OFF[combo];
    float a = 0.f;
    for (int m=0;m<=2*l1;m++){
      int n = M - L - m + l1 + l2;      // m1+m2 == M constraint
      if (n >= 0 && n <= 2*l2){
        float coef = cg[off + (m*(2*l2+1)+n)*(2*L+1) + M];
        a += coef * vb[(MB[l1]+m)*8 + c] * vb[(MB[l2]+n)*8 + d];
      }
    }
    cgb[v] = a;
  }
  __syncthreads();
  if (t < 72){
    int mall = t >> 3, dp = t & 7;
    int l = (mall==0) ? 0 : (mall < 4 ? 1 : 2);
    int M = mall - MB[l];
    const float* wn = (l==0) ? wn0 : (l==1 ? wn1 : wn2);
    int C = (l==0) ? 192 : 384;
    int base = (l==0) ? 0 : (l==1 ? 192 + M*384 : 1344 + M*384);
    float a = 0.f;
    for (int ch=0; ch<C; ch++) a += cgb[base+ch] * wn[ch*8 + dp];
    mixed[i*72 + t] = a;
  }
}

// ---------------- kernel 3: pairwise CG(mixed,s) + wr mix, sum over x ------
#define XCH 4
__global__ __launch_bounds__(256) void k_pair(
    const float* __restrict__ mixed,
    const float* __restrict__ s0, const float* __restrict__ s1, const float* __restrict__ s2,
    const float* __restrict__ wr0, const float* __restrict__ wr1, const float* __restrict__ wr2,
    const float* __restrict__ cg, float* __restrict__ vsum){
  __shared__ float sm[4][88];       // [wave]: mixed 0..71, s 72..80
  __shared__ float cgrel[4][416];   // [wave]: L0: [0,24) L1: 24+M*48 L2: 168+M*48
  int tid = threadIdx.x;
  int wave = tid >> 6, lane = tid & 63;
  int y  = blockIdx.x & 255;
  int xc = blockIdx.x >> 8;
  int xbase = xc * (NN / XCH);
  int cgp = lane >> 3, d = lane & 7;
  float acc[9];
  #pragma unroll
  for (int m=0;m<9;m++) acc[m] = 0.f;

  for (int it=0; it < (NN/XCH)/4; ++it){
    int x = xbase + it*4 + wave;
    long pxy = (long)x*NN + y;
    // phase 1: stage mixed[x] (72) + s[x,y] (9) into this wave's LDS
    sm[wave][lane] = mixed[x*72 + lane];
    if (lane < 8) sm[wave][64+lane] = mixed[x*72 + 64 + lane];
    if (lane < 9){
      float sv;
      if (lane == 0)      sv = s0[pxy];
      else if (lane < 4)  sv = s1[pxy*3 + (lane-1)];
      else                sv = s2[pxy*5 + (lane-4)];
      sm[wave][72+lane] = sv;
    }
    __syncthreads();
    // phase 2: cooperative cg_rel (408 values)
    for (int v = lane; v < 408; v += 64){
      int L, M, ch;
      if (v < 24)       { L=0; M=0;           ch=v; }
      else if (v < 168) { int r=v-24;  L=1; M=r/48; ch=r%48; }
      else              { int r=v-168; L=2; M=r/48; ch=r%48; }
      int chunk = ch >> 3, tc = ch & 7;
      int combo = CHUNK_COMBO[LSTART[L] + chunk];
      int l1 = COMBO_L1[combo], l2 = COMBO_L2[combo], off = COMBO_OFF[combo];
      float a = 0.f;
      for (int m=0;m<=2*l1;m++){
        int n = M - L - m + l1 + l2;
        if (n >= 0 && n <= 2*l2){
          a += cg[off + (m*(2*l2+1)+n)*(2*L+1) + M]
             * sm[wave][(MB[l1]+m)*8 + tc] * sm[wave][72 + MB[l2] + n];
        }
      }
      cgrel[wave][v] = a;
    }
    __syncthreads();
    // phase 3: coalesced wr loads + mix; lane (cgp,d) handles channels c=cgp+8k
    {
      const float* p0 = wr0 + pxy*192;
      #pragma unroll
      for (int k=0;k<3;k++){
        int c = cgp + 8*k;
        acc[0] += cgrel[wave][c] * p0[c*8 + d];
      }
      const float* p1 = wr1 + pxy*384;
      #pragma unroll
      for (int k=0;k<6;k++){
        int c = cgp + 8*k;
        float w = p1[c*8 + d];
        #pragma unroll
        for (int M=0;M<3;M++) acc[1+M] += cgrel[wave][24 + M*48 + c] * w;
      }
      const float* p2 = wr2 + pxy*384;
      #pragma unroll
      for (int k=0;k<6;k++){
        int c = cgp + 8*k;
        float w = p2[c*8 + d];
        #pragma unroll
        for (int M=0;M<5;M++) acc[4+M] += cgrel[wave][168 + M*48 + c] * w;
      }
    }
    __syncthreads();
  }
  // butterfly-reduce over the 8 c-groups (lane bits 3..5)
  #pragma unroll
  for (int m=0;m<9;m++){
    float v = acc[m];
    v += __shfl_xor(v, 8);
    v += __shfl_xor(v, 16);
    v += __shfl_xor(v, 32);
    acc[m] = v;
  }
  if (lane < 8){
    #pragma unroll
    for (int m=0;m<9;m++) atomicAdd(&vsum[y*72 + m*8 + lane], acc[m]);
  }
}

// ---------------- kernel 4a: per-part global sums --------------------------
__global__ void k_psum(const float* __restrict__ vsum, float* __restrict__ psum){
  __shared__ float red[256];
  int t = threadIdx.x, p = blockIdx.x;
  int m0 = (p==0) ? 0 : (p==1 ? 1 : 4);
  int nm = (p==0) ? 1 : (p==1 ? 3 : 5);
  int count = NN * nm * 8;
  float a = 0.f;
  for (int idx = t; idx < count; idx += 256){
    int dd = idx & 7;
    int mm = (idx >> 3) % nm;
    int yy = idx / (8*nm);
    a += vsum[yy*72 + (m0+mm)*8 + dd];
  }
  red[t] = a; __syncthreads();
  for (int s=128; s>0; s>>=1){ if (t < s) red[t] += red[t+s]; __syncthreads(); }
  if (t == 0) psum[p] = red[0];
}

// ---------------- kernel 4b: normalize + write out -------------------------
__global__ void k_norm(const float* __restrict__ vsum, const float* __restrict__ psum,
                       float* __restrict__ out){
  int idx = blockIdx.x*256 + threadIdx.x;
  if (idx >= NN*72) return;
  int mall = (idx >> 3) % 9;
  int l = (mall==0) ? 0 : (mall < 4 ? 1 : 2);
  out[idx] = vsum[idx] / psum[l];
}

extern "C" void kernel_launch(void* const* d_in, const int* in_sizes, int n_in,
                              void* d_out, int out_size, void* d_ws, size_t ws_size,
                              hipStream_t stream) {
  const float* v0  = (const float*)d_in[0];
  const float* v1  = (const float*)d_in[1];
  const float* v2  = (const float*)d_in[2];
  const float* adj = (const float*)d_in[3];
  const float* s0  = (const float*)d_in[4];
  const float* s1  = (const float*)d_in[5];
  const float* s2  = (const float*)d_in[6];
  const float* wn0 = (const float*)d_in[7];
  const float* wn1 = (const float*)d_in[8];
  const float* wn2 = (const float*)d_in[9];
  const float* wr0 = (const float*)d_in[10];
  const float* wr1 = (const float*)d_in[11];
  const float* wr2 = (const float*)d_in[12];
  float* out = (float*)d_out;

  float* ws    = (float*)d_ws;
  float* cg    = ws;                     // 615 (pad 640)
  float* vmp   = ws + 640;               // 18432
  float* mixed = ws + 640 + 18432;       // 18432
  float* vsum  = ws + 640 + 2*18432;     // 18432
  float* psum  = ws + 640 + 3*18432;     // 3

  hipMemsetAsync(vsum, 0, 18432*sizeof(float), stream);
  init_cg<<<1, 64, 0, stream>>>(cg);
  k_vmp<<<NN, 128, 0, stream>>>(adj, v0, v1, v2, vmp);
  k_mixed<<<NN, 256, 0, stream>>>(vmp, wn0, wn1, wn2, cg, mixed);
  k_pair<<<NN*XCH, 256, 0, stream>>>(mixed, s0, s1, s2, wr0, wr1, wr2, cg, vsum);
  k_psum<<<3, 256, 0, stream>>>(vsum, psum);
  k_norm<<<72, 256, 0, stream>>>(vsum, psum, out);
}

// Round 2
// 140.855 us; speedup vs baseline: 2.2060x; 2.2060x over previous
//
#include <hip/hip_runtime.h>

#define NN 256

// ---- combo tables: 15 (l1,l2,L) CG tensors, dense [2l1+1][2l2+1][2L+1] ----
__device__ const int COMBO_L1[15]  = {0,0,1,1,1,1,0,2,1,2,1,2,2,2,2};
__device__ const int COMBO_L2[15]  = {0,1,0,1,1,1,2,0,2,1,2,1,2,2,2};
__device__ const int COMBO_LL[15]  = {0,1,1,0,1,2,2,2,1,1,2,2,0,1,2};
__device__ const int COMBO_OFF[15] = {0,1,10,19,28,55,100,125,150,195,240,315,390,415,490};
__device__ const int CHUNK_COMBO[15] = {0,3,12, 1,2,4,8,9,13, 6,5,10,7,11,14};
__device__ const int LSTART[3] = {0,3,9};
__device__ const int MB[3] = {0,1,4};

// hard-coded CG constants (l<=2), float32
#define C13  0.5773502691896258f   // 1/sqrt(3)
#define C15  0.4472135954999579f   // 1/sqrt(5)
#define CC12 0.7071067811865476f   // 1/sqrt(2)
#define S35  0.7745966692414834f   // sqrt(3/5)
#define S310 0.5477225575051661f   // sqrt(3/10)
#define C110 0.3162277660168379f   // 1/sqrt(10)
#define S25  0.6324555320336759f   // sqrt(2/5)
#define S23  0.8164965809277260f   // sqrt(2/3)
#define C16  0.4082482904638630f   // 1/sqrt(6)
#define S27  0.5345224838248488f   // sqrt(2/7)
#define S37  0.6546536707079771f   // sqrt(3/7)
#define C114 0.2672612419124244f   // 1/sqrt(14)

// ---------------- CG coefficient init (for k_mixed table) ------------------
__device__ double dfact(int n){ double r=1.0; for(int i=2;i<=n;i++) r*=i; return r; }

__device__ double cg_coeff(int j1,int m1,int j2,int m2,int J,int M){
  if (m1+m2 != M || J < abs(j1-j2) || J > j1+j2) return 0.0;
  double pre = sqrt((2.0*J+1.0)*dfact(J+j1-j2)*dfact(J-j1+j2)*dfact(j1+j2-J)/dfact(j1+j2+J+1));
  pre *= sqrt(dfact(J+M)*dfact(J-M)*dfact(j1-m1)*dfact(j1+m1)*dfact(j2-m2)*dfact(j2+m2));
  int kmin = max(0, max(j2-J-m1, j1+m2-J));
  int kmax = min(j1+j2-J, min(j1-m1, j2+m2));
  double s = 0.0;
  for (int k=kmin;k<=kmax;k++){
    double den = dfact(k)*dfact(j1+j2-J-k)*dfact(j1-m1-k)*dfact(j2+m2-k)*dfact(J-j2+m1+k)*dfact(J-j1-m2+k);
    s += ((k&1)?-1.0:1.0)/den;
  }
  return pre*s;
}

__global__ void init_cg(float* cg){
  int t = threadIdx.x;
  if (t >= 15) return;
  int l1 = COMBO_L1[t], l2 = COMBO_L2[t], L = COMBO_LL[t], off = COMBO_OFF[t];
  int sz = (2*l1+1)*(2*l2+1)*(2*L+1);
  for (int i=0;i<sz;i++) cg[off+i] = 0.f;
  for (int m1=-l1;m1<=l1;m1++)
    for (int m2=-l2;m2<=l2;m2++){
      int M = m1+m2;
      if (M >= -L && M <= L)
        cg[off + ((m1+l1)*(2*l2+1) + (m2+l2))*(2*L+1) + (M+L)] = (float)cg_coeff(l1,m1,l2,m2,L,M);
    }
}

// ---------------- kernel 1: vmp = adj @ v  -> [256][72] --------------------
__global__ void k_vmp(const float* __restrict__ adj,
                      const float* __restrict__ v0,
                      const float* __restrict__ v1,
                      const float* __restrict__ v2,
                      float* __restrict__ vmp){
  int i = blockIdx.x;
  int t = threadIdx.x;
  if (t >= 72) return;
  int mall = t >> 3, c = t & 7;
  int l = (mall==0) ? 0 : (mall < 4 ? 1 : 2);
  int m = mall - MB[l];
  const float* v = (l==0) ? v0 : (l==1 ? v1 : v2);
  int stride = (2*l+1)*8;
  const float* arow = adj + i*NN;
  float acc = 0.f;
  for (int j=0;j<NN;j++) acc += arow[j] * v[j*stride + m*8 + c];
  vmp[i*72 + t] = acc;
}

// ---------------- kernel 2: per-node CG(vmp,vmp) + wn mix -> mixed[256][72]
__global__ void k_mixed(const float* __restrict__ vmp,
                        const float* __restrict__ wn0,
                        const float* __restrict__ wn1,
                        const float* __restrict__ wn2,
                        const float* __restrict__ cg,
                        float* __restrict__ mixed){
  __shared__ float vb[72];
  __shared__ float cgb[3264];
  int i = blockIdx.x;
  int t = threadIdx.x;
  if (t < 72) vb[t] = vmp[i*72 + t];
  __syncthreads();
  for (int v = t; v < 3264; v += blockDim.x){
    int L, M, ch;
    if (v < 192)       { L=0; M=0;            ch=v; }
    else if (v < 1344) { int r=v-192;  L=1; M=r/384; ch=r%384; }
    else               { int r=v-1344; L=2; M=r/384; ch=r%384; }
    int chunk = ch >> 6, rem = ch & 63, c = rem >> 3, d = rem & 7;
    int combo = CHUNK_COMBO[LSTART[L] + chunk];
    int l1 = COMBO_L1[combo], l2 = COMBO_L2[combo], off = COMBO_OFF[combo];
    float a = 0.f;
    for (int m=0;m<=2*l1;m++){
      int n = M - L - m + l1 + l2;
      if (n >= 0 && n <= 2*l2){
        float coef = cg[off + (m*(2*l2+1)+n)*(2*L+1) + M];
        a += coef * vb[(MB[l1]+m)*8 + c] * vb[(MB[l2]+n)*8 + d];
      }
    }
    cgb[v] = a;
  }
  __syncthreads();
  if (t < 72){
    int mall = t >> 3, dp = t & 7;
    int l = (mall==0) ? 0 : (mall < 4 ? 1 : 2);
    int M = mall - MB[l];
    const float* wn = (l==0) ? wn0 : (l==1 ? wn1 : wn2);
    int C = (l==0) ? 192 : 384;
    int base = (l==0) ? 0 : (l==1 ? 192 + M*384 : 1344 + M*384);
    float a = 0.f;
    for (int ch=0; ch<C; ch++) a += cgb[base+ch] * wn[ch*8 + dp];
    mixed[i*72 + t] = a;
  }
}

// ---------------- kernel 3: pairwise CG(mixed,s) + wr mix, sum over x ------
// One fully-independent wave per (y, x-chunk). No LDS, no barriers.
// Lane = (cgp, d): handles cg channels c = cgp+8k, output tau d.
#define XPW 16
__global__ __launch_bounds__(256) void k_pair(
    const float* __restrict__ mixed,
    const float* __restrict__ s0, const float* __restrict__ s1, const float* __restrict__ s2,
    const float* __restrict__ wr0, const float* __restrict__ wr1, const float* __restrict__ wr2,
    float* __restrict__ vsum){
  int tid = threadIdx.x;
  int lane = tid & 63;
  int w = blockIdx.x*4 + (tid>>6);
  int y = w & (NN-1);
  int xbase = (w >> 8) * XPW;
  int cgp = lane >> 3;

  float acc[9];
  #pragma unroll
  for (int m=0;m<9;m++) acc[m]=0.f;

  float mx[9], sv[9];
  {
    const float* mb = mixed + xbase*72 + cgp;
    #pragma unroll
    for (int j=0;j<9;j++) mx[j] = mb[j*8];
    int pxy = xbase*NN + y;
    sv[0] = s0[pxy];
    #pragma unroll
    for (int j=0;j<3;j++) sv[1+j] = s1[pxy*3+j];
    #pragma unroll
    for (int j=0;j<5;j++) sv[4+j] = s2[pxy*5+j];
  }

  for (int i=0;i<XPW;i++){
    int x = xbase + i;
    int pxy = x*NN + y;
    // issue wr loads early (consumed ~200 VALU ops later)
    const float* p0 = wr0 + pxy*192 + lane;
    const float* p1 = wr1 + pxy*384 + lane;
    const float* p2 = wr2 + pxy*384 + lane;
    float w0[3], w1[6], w2[6];
    #pragma unroll
    for (int k=0;k<3;k++) w0[k] = p0[k*64];
    #pragma unroll
    for (int k=0;k<6;k++) w1[k] = p1[k*64];
    #pragma unroll
    for (int k=0;k<6;k++) w2[k] = p2[k*64];

    // prefetch next pair's mixed/s
    float nmx[9], nsv[9];
    {
      int xn = x + ((i < XPW-1) ? 1 : 0);
      const float* mb = mixed + xn*72 + cgp;
      #pragma unroll
      for (int j=0;j<9;j++) nmx[j] = mb[j*8];
      int pn = xn*NN + y;
      nsv[0] = s0[pn];
      #pragma unroll
      for (int j=0;j<3;j++) nsv[1+j] = s1[pn*3+j];
      #pragma unroll
      for (int j=0;j<5;j++) nsv[4+j] = s2[pn*5+j];
    }

    // ---- cgrel: hard-coded CG contraction (per-lane, tc = cgp) ----
    // L=0: chunks (0,0),(1,1),(2,2)
    float r0[3];
    r0[0] = mx[0]*sv[0];
    r0[1] = C13*(mx[1]*sv[3] - mx[2]*sv[2] + mx[3]*sv[1]);
    r0[2] = C15*(mx[4]*sv[8] - mx[5]*sv[7] + mx[6]*sv[6] - mx[7]*sv[5] + mx[8]*sv[4]);
    // L=1: chunks (0,1),(1,0),(1,1),(1,2),(2,1),(2,2); Mi = M+1
    float r1[3][6];
    r1[0][0] = mx[0]*sv[1]; r1[1][0] = mx[0]*sv[2]; r1[2][0] = mx[0]*sv[3];
    r1[0][1] = mx[1]*sv[0]; r1[1][1] = mx[2]*sv[0]; r1[2][1] = mx[3]*sv[0];
    r1[0][2] = CC12*(mx[2]*sv[1] - mx[1]*sv[2]);
    r1[1][2] = CC12*(mx[3]*sv[1] - mx[1]*sv[3]);
    r1[2][2] = CC12*(mx[3]*sv[2] - mx[2]*sv[3]);
    r1[0][3] = S35*mx[3]*sv[4] - S310*mx[2]*sv[5] + C110*mx[1]*sv[6];
    r1[1][3] = S310*(mx[3]*sv[5] + mx[1]*sv[7]) - S25*mx[2]*sv[6];
    r1[2][3] = S35*mx[1]*sv[8] - S310*mx[2]*sv[7] + C110*mx[3]*sv[6];
    r1[0][4] = C110*mx[6]*sv[1] - S310*mx[5]*sv[2] + S35*mx[4]*sv[3];
    r1[1][4] = S310*(mx[7]*sv[1] + mx[5]*sv[3]) - S25*mx[6]*sv[2];
    r1[2][4] = S35*mx[8]*sv[1] - S310*mx[7]*sv[2] + C110*mx[6]*sv[3];
    r1[0][5] = C15*(mx[7]*sv[4] - mx[4]*sv[7]) + S310*(mx[5]*sv[6] - mx[6]*sv[5]);
    r1[1][5] = S25*(mx[8]*sv[4] - mx[4]*sv[8]) + C110*(mx[5]*sv[7] - mx[7]*sv[5]);
    r1[2][5] = C15*(mx[8]*sv[5] - mx[5]*sv[8]) + S310*(mx[6]*sv[7] - mx[7]*sv[6]);
    // L=2: chunks (0,2),(1,1),(1,2),(2,0),(2,1),(2,2); Mi = M+2
    float r2[5][6];
    r2[0][0]=mx[0]*sv[4]; r2[1][0]=mx[0]*sv[5]; r2[2][0]=mx[0]*sv[6]; r2[3][0]=mx[0]*sv[7]; r2[4][0]=mx[0]*sv[8];
    r2[0][1] = mx[1]*sv[1];
    r2[1][1] = CC12*(mx[2]*sv[1] + mx[1]*sv[2]);
    r2[2][1] = C16*(mx[3]*sv[1] + mx[1]*sv[3]) + S23*mx[2]*sv[2];
    r2[3][1] = CC12*(mx[3]*sv[2] + mx[2]*sv[3]);
    r2[4][1] = mx[3]*sv[3];
    r2[0][2] = S23*mx[2]*sv[4] - C13*mx[1]*sv[5];
    r2[1][2] = C13*mx[3]*sv[4] + C16*mx[2]*sv[5] - CC12*mx[1]*sv[6];
    r2[2][2] = CC12*(mx[3]*sv[5] - mx[1]*sv[7]);
    r2[3][2] = CC12*mx[3]*sv[6] - C16*mx[2]*sv[7] - C13*mx[1]*sv[8];
    r2[4][2] = C13*mx[3]*sv[7] - S23*mx[2]*sv[8];
    r2[0][3]=mx[4]*sv[0]; r2[1][3]=mx[5]*sv[0]; r2[2][3]=mx[6]*sv[0]; r2[3][3]=mx[7]*sv[0]; r2[4][3]=mx[8]*sv[0];
    r2[0][4] = C13*mx[5]*sv[1] - S23*mx[4]*sv[2];
    r2[1][4] = CC12*mx[6]*sv[1] - C16*mx[5]*sv[2] - C13*mx[4]*sv[3];
    r2[2][4] = CC12*(mx[7]*sv[1] - mx[5]*sv[3]);
    r2[3][4] = C13*mx[8]*sv[1] + C16*mx[7]*sv[2] - CC12*mx[6]*sv[3];
    r2[4][4] = S23*mx[8]*sv[2] - C13*mx[7]*sv[3];
    r2[0][5] = S27*(mx[4]*sv[6] + mx[6]*sv[4]) - S37*mx[5]*sv[5];
    r2[1][5] = S37*(mx[4]*sv[7] + mx[7]*sv[4]) - C114*(mx[5]*sv[6] + mx[6]*sv[5]);
    r2[2][5] = S27*(mx[8]*sv[4] + mx[4]*sv[8] - mx[6]*sv[6]) + C114*(mx[7]*sv[5] + mx[5]*sv[7]);
    r2[3][5] = S37*(mx[8]*sv[5] + mx[5]*sv[8]) - C114*(mx[7]*sv[6] + mx[6]*sv[7]);
    r2[4][5] = S27*(mx[8]*sv[6] + mx[6]*sv[8]) - S37*mx[7]*sv[7];

    // ---- FMA with wr ----
    #pragma unroll
    for (int k=0;k<3;k++) acc[0] = fmaf(r0[k], w0[k], acc[0]);
    #pragma unroll
    for (int k=0;k<6;k++){
      acc[1] = fmaf(r1[0][k], w1[k], acc[1]);
      acc[2] = fmaf(r1[1][k], w1[k], acc[2]);
      acc[3] = fmaf(r1[2][k], w1[k], acc[3]);
      acc[4] = fmaf(r2[0][k], w2[k], acc[4]);
      acc[5] = fmaf(r2[1][k], w2[k], acc[5]);
      acc[6] = fmaf(r2[2][k], w2[k], acc[6]);
      acc[7] = fmaf(r2[3][k], w2[k], acc[7]);
      acc[8] = fmaf(r2[4][k], w2[k], acc[8]);
    }
    #pragma unroll
    for (int j=0;j<9;j++){ mx[j]=nmx[j]; sv[j]=nsv[j]; }
  }

  // reduce over cgp groups (lane bits 3..5)
  #pragma unroll
  for (int m=0;m<9;m++){
    float v = acc[m];
    v += __shfl_xor(v, 8);
    v += __shfl_xor(v, 16);
    v += __shfl_xor(v, 32);
    acc[m] = v;
  }
  if (lane < 8){
    #pragma unroll
    for (int m=0;m<9;m++) atomicAdd(&vsum[y*72 + m*8 + lane], acc[m]);
  }
}

// ---------------- kernel 4a: per-part global sums --------------------------
__global__ void k_psum(const float* __restrict__ vsum, float* __restrict__ psum){
  __shared__ float red[256];
  int t = threadIdx.x, p = blockIdx.x;
  int m0 = (p==0) ? 0 : (p==1 ? 1 : 4);
  int nm = (p==0) ? 1 : (p==1 ? 3 : 5);
  int count = NN * nm * 8;
  float a = 0.f;
  for (int idx = t; idx < count; idx += 256){
    int dd = idx & 7;
    int mm = (idx >> 3) % nm;
    int yy = idx / (8*nm);
    a += vsum[yy*72 + (m0+mm)*8 + dd];
  }
  red[t] = a; __syncthreads();
  for (int s=128; s>0; s>>=1){ if (t < s) red[t] += red[t+s]; __syncthreads(); }
  if (t == 0) psum[p] = red[0];
}

// ---------------- kernel 4b: normalize + write out -------------------------
__global__ void k_norm(const float* __restrict__ vsum, const float* __restrict__ psum,
                       float* __restrict__ out){
  int idx = blockIdx.x*256 + threadIdx.x;
  if (idx >= NN*72) return;
  int mall = (idx >> 3) % 9;
  int l = (mall==0) ? 0 : (mall < 4 ? 1 : 2);
  out[idx] = vsum[idx] / psum[l];
}

extern "C" void kernel_launch(void* const* d_in, const int* in_sizes, int n_in,
                              void* d_out, int out_size, void* d_ws, size_t ws_size,
                              hipStream_t stream) {
  const float* v0  = (const float*)d_in[0];
  const float* v1  = (const float*)d_in[1];
  const float* v2  = (const float*)d_in[2];
  const float* adj = (const float*)d_in[3];
  const float* s0  = (const float*)d_in[4];
  const float* s1  = (const float*)d_in[5];
  const float* s2  = (const float*)d_in[6];
  const float* wn0 = (const float*)d_in[7];
  const float* wn1 = (const float*)d_in[8];
  const float* wn2 = (const float*)d_in[9];
  const float* wr0 = (const float*)d_in[10];
  const float* wr1 = (const float*)d_in[11];
  const float* wr2 = (const float*)d_in[12];
  float* out = (float*)d_out;

  float* ws    = (float*)d_ws;
  float* cg    = ws;                     // 615 (pad 640)
  float* vmp   = ws + 640;               // 18432
  float* mixed = ws + 640 + 18432;       // 18432
  float* vsum  = ws + 640 + 2*18432;     // 18432
  float* psum  = ws + 640 + 3*18432;     // 3

  hipMemsetAsync(vsum, 0, 18432*sizeof(float), stream);
  init_cg<<<1, 64, 0, stream>>>(cg);
  k_vmp<<<NN, 128, 0, stream>>>(adj, v0, v1, v2, vmp);
  k_mixed<<<NN, 256, 0, stream>>>(vmp, wn0, wn1, wn2, cg, mixed);
  k_pair<<<NN*(NN/XPW)/4, 256, 0, stream>>>(mixed, s0, s1, s2, wr0, wr1, wr2, vsum);
  k_psum<<<3, 256, 0, stream>>>(vsum, psum);
  k_norm<<<72, 256, 0, stream>>>(vsum, psum, out);
}